// Round 1
// baseline (594.995 us; speedup 1.0000x reference)
//
#include <hip/hip_runtime.h>

// Problem: B=2, S=2048, D=2048, H=16, DH=128. All inputs fp32, output fp32.
// Pipeline: cast/transpose -> QKV GEMMs (bf16 MFMA) -> flash attention (bf16 MFMA)
//           -> LN1 -> FF GEMM -> LN2.
// O is kept in [B,H,S,DH] natural layout; the reference's "buggy concat" is a
// flat view of that as [B,S,D], so LN kernels simply index it flat.

#define B_ 2
#define S_ 2048
#define D_ 2048
#define H_ 16
#define DH_ 128

typedef __attribute__((ext_vector_type(8))) short s16x8;
typedef __attribute__((ext_vector_type(4))) float f32x4;
typedef __attribute__((ext_vector_type(4))) unsigned short u16x4;

#define MFMA16(a, b, c) __builtin_amdgcn_mfma_f32_16x16x32_bf16(a, b, c, 0, 0, 0)

__device__ inline unsigned short f2bf(float f) {
  union { float f; unsigned u; } x; x.f = f;
  unsigned r = (x.u + 0x7fffu + ((x.u >> 16) & 1u)) >> 16;  // RNE
  return (unsigned short)r;
}
__device__ inline float bf2f(unsigned short u) {
  union { unsigned u; float f; } x; x.u = ((unsigned)u) << 16;
  return x.f;
}

// async global->LDS, 16B per lane. LDS dest is wave-uniform base + lane*16,
// so callers must pass lane-contiguous chunk indices.
__device__ inline void gld_lds16(const void* g, void* l) {
  __builtin_amdgcn_global_load_lds(
      (__attribute__((address_space(1))) void*)g,
      (__attribute__((address_space(3))) void*)l, 16, 0, 0);
}

// ---------------------------------------------------------------- cast x
__global__ __launch_bounds__(256) void cast_x_kernel(
    const float* __restrict__ x, unsigned short* __restrict__ xb) {
  int i = (blockIdx.x * 256 + threadIdx.x) * 4;  // grid 8192 covers 8388608
  float4 v = *(const float4*)&x[i];
  u16x4 o;
  o.x = f2bf(v.x); o.y = f2bf(v.y); o.z = f2bf(v.z); o.w = f2bf(v.w);
  *(u16x4*)&xb[i] = o;
}

// ------------------------------------------- weight transpose+cast: WT[n][k]=W[k][n]
// 64x64 tiles; coalesced float4 reads, scattered 2B writes (L2 write-combines:
// each 128B WT line is fully covered by one block).
__global__ __launch_bounds__(256) void transpose_w_kernel(
    const float* __restrict__ W, unsigned short* __restrict__ WT) {
  int t = threadIdx.x;
  int n0 = blockIdx.x * 64, k0 = blockIdx.y * 64;
  int cl = t & 15, rw = t >> 4;
#pragma unroll
  for (int p = 0; p < 4; ++p) {
    int k = k0 + rw + p * 16;
    float4 v = *(const float4*)&W[k * D_ + n0 + cl * 4];
    WT[(n0 + cl * 4 + 0) * D_ + k] = f2bf(v.x);
    WT[(n0 + cl * 4 + 1) * D_ + k] = f2bf(v.y);
    WT[(n0 + cl * 4 + 2) * D_ + k] = f2bf(v.z);
    WT[(n0 + cl * 4 + 3) * D_ + k] = f2bf(v.w);
  }
}

// ------------------------------------------- V transpose: VT[bh][d][s] = V[b*S+s][h*DH+d]
__global__ __launch_bounds__(256) void transpose_v_kernel(
    const unsigned short* __restrict__ V, unsigned short* __restrict__ VT) {
  int t = threadIdx.x;
  int s0 = blockIdx.x * 64, d0 = blockIdx.y * 64, bh = blockIdx.z;
  int b = bh >> 4, h = bh & 15;
  int cl = t & 15, rw = t >> 4;
#pragma unroll
  for (int p = 0; p < 4; ++p) {
    int s = s0 + rw + p * 16;
    u16x4 v = *(const u16x4*)&V[(b * S_ + s) * D_ + h * DH_ + d0 + cl * 4];
    VT[(bh * DH_ + d0 + cl * 4 + 0) * S_ + s] = v.x;
    VT[(bh * DH_ + d0 + cl * 4 + 1) * S_ + s] = v.y;
    VT[(bh * DH_ + d0 + cl * 4 + 2) * S_ + s] = v.z;
    VT[(bh * DH_ + d0 + cl * 4 + 3) * S_ + s] = v.w;
  }
}

// ------------------------------------------- GEMM: C[M=4096][N=2048] = A[M][K=2048] * BT[N][K]^T + bias
// m97 structure: 128x128 tile, BK=32, 256 thr (4 waves 2x2, each 64x64 = 4x4 MFMA tiles).
template <int OUTF32>
__global__ __launch_bounds__(256) void gemm_bt_kernel(
    const unsigned short* __restrict__ A, const unsigned short* __restrict__ BT,
    const float* __restrict__ bias, void* __restrict__ Cout) {
  __shared__ short As[128 * 32];
  __shared__ short Bs[128 * 32];
  int t = threadIdx.x, lane = t & 63, w = t >> 6;
  int nl = lane & 15, q = lane >> 4;
  int m0 = blockIdx.y * 128, n0 = blockIdx.x * 128;
  int wr = (w >> 1) * 64, wc = (w & 1) * 64;

  f32x4 acc[4][4];
  f32x4 z4 = {0.f, 0.f, 0.f, 0.f};
#pragma unroll
  for (int i = 0; i < 4; ++i)
#pragma unroll
    for (int j = 0; j < 4; ++j) acc[i][j] = z4;

  for (int kk = 0; kk < 2048; kk += 32) {
    __syncthreads();
#pragma unroll
    for (int i2 = 0; i2 < 2; ++i2) {
      int c = t + 256 * i2;  // 512 chunks per 128x32 tile
      int row = c >> 2, dc = c & 3;
      gld_lds16(&A[(m0 + row) * 2048 + kk + dc * 8], &As[c * 8]);
      gld_lds16(&BT[(n0 + row) * 2048 + kk + dc * 8], &Bs[c * 8]);
    }
    __syncthreads();
    s16x8 af[4], bf[4];
#pragma unroll
    for (int i = 0; i < 4; ++i)
      af[i] = *(const s16x8*)&As[(wr + i * 16 + nl) * 32 + q * 8];
#pragma unroll
    for (int j = 0; j < 4; ++j)
      bf[j] = *(const s16x8*)&Bs[(wc + j * 16 + nl) * 32 + q * 8];
#pragma unroll
    for (int i = 0; i < 4; ++i)
#pragma unroll
      for (int j = 0; j < 4; ++j) acc[i][j] = MFMA16(af[i], bf[j], acc[i][j]);
  }
  // epilogue: C/D layout col=lane&15, row=quad*4+reg
#pragma unroll
  for (int i = 0; i < 4; ++i)
#pragma unroll
    for (int j = 0; j < 4; ++j) {
      int row = m0 + wr + i * 16 + q * 4;
      int col = n0 + wc + j * 16 + nl;
      float bv = bias[col];
#pragma unroll
      for (int r = 0; r < 4; ++r) {
        float v = acc[i][j][r] + bv;
        if (OUTF32)
          ((float*)Cout)[(row + r) * 2048 + col] = v;
        else
          ((unsigned short*)Cout)[(row + r) * 2048 + col] = f2bf(v);
      }
    }
}

// ------------------------------------------- flash attention
// Block = (bh, q-tile of 128). 4 waves, each owns 32 Q rows (2 row-tiles of 16).
// KV tiles of 64. K staged into 4 LDS slabs [64][32] (m97 layout); V^T staged
// with XOR chunk swizzle so PV B-frags are conflict-free ds_read_b128.
// P goes through padded LDS (C-layout -> A-layout transform).
__global__ __launch_bounds__(256) void attn_kernel(
    const unsigned short* __restrict__ Q, const unsigned short* __restrict__ K,
    const unsigned short* __restrict__ VT, unsigned short* __restrict__ O) {
  __shared__ short Ks[4 * 64 * 32];   // 16KB: [kc][s 0..63][32]
  __shared__ short Vs[128 * 64];      // 16KB: chunk-swizzled [d][s]
  __shared__ short Ps[4 * 32 * 72];   // 18KB: per wave [32][72] (pad 8 -> 144B rows)
  int t = threadIdx.x, lane = t & 63, w = t >> 6;
  int nl = lane & 15, q = lane >> 4;
  int bx = blockIdx.x;
  int qb = bx & 15, bh = bx >> 4;
  int b = bh >> 4, h = bh & 15;
  const float scl2 = 0.08838834764831845f * 1.4426950408889634f;  // 1/sqrt(128)*log2(e)

  // Q fragments live in registers for the whole kernel
  s16x8 qf[2][4];
  int qrow = b * S_ + qb * 128 + w * 32;
#pragma unroll
  for (int t2 = 0; t2 < 2; ++t2)
#pragma unroll
    for (int kc = 0; kc < 4; ++kc)
      qf[t2][kc] = *(const s16x8*)&Q[(qrow + t2 * 16 + nl) * D_ + h * DH_ + kc * 32 + q * 8];

  f32x4 z4 = {0.f, 0.f, 0.f, 0.f};
  f32x4 accO[2][8];
  f32x4 m_i[2], l_i[2];
#pragma unroll
  for (int t2 = 0; t2 < 2; ++t2) {
    l_i[t2] = z4;
    m_i[t2] = (f32x4){-1e30f, -1e30f, -1e30f, -1e30f};
#pragma unroll
    for (int n8 = 0; n8 < 8; ++n8) accO[t2][n8] = z4;
  }

  for (int kv = 0; kv < S_; kv += 64) {
    __syncthreads();
#pragma unroll
    for (int i2 = 0; i2 < 4; ++i2) {
      int c = t + 256 * i2;  // 1024 chunks each for K-tile and V-tile
      {
        int kc = c >> 8, rem = c & 255, s = rem >> 2, dc = rem & 3;
        gld_lds16(&K[(b * S_ + kv + s) * D_ + h * DH_ + kc * 32 + dc * 8], &Ks[c * 8]);
      }
      {
        int d = c >> 3, cp = c & 7, cs = cp ^ (d & 7);
        gld_lds16(&VT[(bh * DH_ + d) * S_ + kv + cs * 8], &Vs[c * 8]);
      }
    }
    __syncthreads();

    // S = Q K^T
    f32x4 accS[2][4];
#pragma unroll
    for (int t2 = 0; t2 < 2; ++t2)
#pragma unroll
      for (int n = 0; n < 4; ++n) accS[t2][n] = z4;
#pragma unroll
    for (int kc = 0; kc < 4; ++kc) {
      s16x8 kf[4];
#pragma unroll
      for (int n = 0; n < 4; ++n)
        kf[n] = *(const s16x8*)&Ks[kc * 2048 + (n * 16 + nl) * 32 + q * 8];
#pragma unroll
      for (int t2 = 0; t2 < 2; ++t2)
#pragma unroll
        for (int n = 0; n < 4; ++n)
          accS[t2][n] = MFMA16(qf[t2][kc], kf[n], accS[t2][n]);
    }

    // online softmax (rows = quad*4+r within each 16-row tile; 16 lanes share a row)
    int pw = w * (32 * 72);
#pragma unroll
    for (int t2 = 0; t2 < 2; ++t2) {
#pragma unroll
      for (int n = 0; n < 4; ++n) accS[t2][n] *= scl2;
      float alph[4];
#pragma unroll
      for (int r = 0; r < 4; ++r) {
        float mx = fmaxf(fmaxf(accS[t2][0][r], accS[t2][1][r]),
                         fmaxf(accS[t2][2][r], accS[t2][3][r]));
#pragma unroll
        for (int mk = 1; mk < 16; mk <<= 1) mx = fmaxf(mx, __shfl_xor(mx, mk));
        float mold = m_i[t2][r];
        float mnew = fmaxf(mold, mx);
        float alpha = exp2f(mold - mnew);
        m_i[t2][r] = mnew;
        float ps = 0.f;
#pragma unroll
        for (int n = 0; n < 4; ++n) {
          float p = exp2f(accS[t2][n][r] - mnew);
          accS[t2][n][r] = p;
          ps += p;
        }
#pragma unroll
        for (int mk = 1; mk < 16; mk <<= 1) ps += __shfl_xor(ps, mk);
        l_i[t2][r] = l_i[t2][r] * alpha + ps;
        alph[r] = alpha;
      }
      f32x4 av = {alph[0], alph[1], alph[2], alph[3]};
#pragma unroll
      for (int n8 = 0; n8 < 8; ++n8) accO[t2][n8] *= av;
      // P: C-layout -> LDS (A-layout read below)
#pragma unroll
      for (int n = 0; n < 4; ++n)
#pragma unroll
        for (int r = 0; r < 4; ++r)
          Ps[pw + (t2 * 16 + q * 4 + r) * 72 + n * 16 + nl] =
              (short)f2bf(accS[t2][n][r]);
    }

    // O += P V   (per-wave private Ps: no barrier needed, lgkmcnt ordering suffices)
#pragma unroll
    for (int ks = 0; ks < 2; ++ks) {
      s16x8 pf[2];
#pragma unroll
      for (int t2 = 0; t2 < 2; ++t2)
        pf[t2] = *(const s16x8*)&Ps[pw + (t2 * 16 + nl) * 72 + ks * 32 + q * 8];
#pragma unroll
      for (int n8 = 0; n8 < 8; ++n8) {
        int d = n8 * 16 + nl;
        int cs = ks * 4 + q;
        int ci = d * 8 + (cs ^ (d & 7));
        s16x8 vf = *(const s16x8*)&Vs[ci * 8];
#pragma unroll
        for (int t2 = 0; t2 < 2; ++t2)
          accO[t2][n8] = MFMA16(pf[t2], vf, accO[t2][n8]);
      }
    }
  }

  // normalize + store O in [B,H,S,DH] natural layout (bf16)
#pragma unroll
  for (int t2 = 0; t2 < 2; ++t2)
#pragma unroll
    for (int r = 0; r < 4; ++r) {
      float inv = 1.0f / l_i[t2][r];
      int row = bh * S_ + qb * 128 + w * 32 + t2 * 16 + q * 4 + r;
#pragma unroll
      for (int n8 = 0; n8 < 8; ++n8)
        O[row * DH_ + n8 * 16 + nl] = f2bf(accO[t2][n8][r] * inv);
    }
}

// ------------------------------------------- LayerNorm: out = LN(A + O_flat)*gamma + beta
template <int OUTBF>
__global__ __launch_bounds__(256) void ln_kernel(
    const float* __restrict__ A, const unsigned short* __restrict__ Ob,
    const float* __restrict__ gamma, const float* __restrict__ beta,
    void* __restrict__ out) {
  int row = blockIdx.x, t = threadIdx.x;
  int lane = t & 63, w = t >> 6;
  float v[8], s = 0.f, s2 = 0.f;
#pragma unroll
  for (int p = 0; p < 8; ++p) {
    int c = t + p * 256;
    float a = A[row * D_ + c] + bf2f(Ob[row * D_ + c]);
    v[p] = a; s += a; s2 += a * a;
  }
#pragma unroll
  for (int mk = 32; mk >= 1; mk >>= 1) {
    s += __shfl_xor(s, mk);
    s2 += __shfl_xor(s2, mk);
  }
  __shared__ float red[8];
  if (lane == 0) { red[w * 2] = s; red[w * 2 + 1] = s2; }
  __syncthreads();
  s = red[0] + red[2] + red[4] + red[6];
  s2 = red[1] + red[3] + red[5] + red[7];
  float mu = s * (1.0f / D_);
  float var = s2 * (1.0f / D_) - mu * mu;
  float rs = rsqrtf(var + 1e-5f);
#pragma unroll
  for (int p = 0; p < 8; ++p) {
    int c = t + p * 256;
    float o = (v[p] - mu) * rs * gamma[c] + beta[c];
    if (OUTBF)
      ((unsigned short*)out)[row * D_ + c] = f2bf(o);
    else
      ((float*)out)[row * D_ + c] = o;
  }
}

// ------------------------------------------- launch
extern "C" void kernel_launch(void* const* d_in, const int* in_sizes, int n_in,
                              void* d_out, int out_size, void* d_ws, size_t ws_size,
                              hipStream_t stream) {
  const float* x     = (const float*)d_in[0];
  const float* wq    = (const float*)d_in[1];
  const float* bq    = (const float*)d_in[2];
  const float* wk    = (const float*)d_in[3];
  const float* bk    = (const float*)d_in[4];
  const float* wv    = (const float*)d_in[5];
  const float* bv    = (const float*)d_in[6];
  const float* wf    = (const float*)d_in[7];
  const float* bfb   = (const float*)d_in[8];
  const float* gamma = (const float*)d_in[9];
  const float* beta  = (const float*)d_in[10];

  // workspace layout (ushort elements); total 112 MiB with aliasing
  unsigned short* ws  = (unsigned short*)d_ws;
  unsigned short* WqT = ws;                       // 4 weights bf16^T, 8MB each
  unsigned short* WkT = ws + 4194304;
  unsigned short* WvT = ws + 8388608;
  unsigned short* WfT = ws + 12582912;
  unsigned short* Xb  = ws + 16777216;            // x bf16, 16MB
  unsigned short* Qb  = ws + 25165824;            // 16MB
  unsigned short* Kb  = ws + 33554432;            // 16MB
  unsigned short* Vb  = ws + 41943040;            // 16MB
  unsigned short* Vt  = ws + 50331648;            // 16MB
  unsigned short* Ob  = Xb;                       // O bf16 over Xb (dead after QKV GEMMs)
  unsigned short* H1  = Kb;                       // h1 bf16 over Kb (dead after attn)
  float* H2 = (float*)(ws + 41943040);            // h2 fp32 over Vb+Vt (32MB)

  dim3 blk(256);
  cast_x_kernel<<<dim3(8192), blk, 0, stream>>>(x, Xb);
  dim3 tg(32, 32);
  transpose_w_kernel<<<tg, blk, 0, stream>>>(wq, WqT);
  transpose_w_kernel<<<tg, blk, 0, stream>>>(wk, WkT);
  transpose_w_kernel<<<tg, blk, 0, stream>>>(wv, WvT);
  transpose_w_kernel<<<tg, blk, 0, stream>>>(wf, WfT);

  dim3 gg(16, 32);  // N-tiles x M-tiles
  gemm_bt_kernel<0><<<gg, blk, 0, stream>>>(Xb, WqT, bq, (void*)Qb);
  gemm_bt_kernel<0><<<gg, blk, 0, stream>>>(Xb, WkT, bk, (void*)Kb);
  gemm_bt_kernel<0><<<gg, blk, 0, stream>>>(Xb, WvT, bv, (void*)Vb);

  transpose_v_kernel<<<dim3(32, 2, 32), blk, 0, stream>>>(Vb, Vt);
  attn_kernel<<<dim3(512), blk, 0, stream>>>(Qb, Kb, Vt, Ob);

  ln_kernel<1><<<dim3(4096), blk, 0, stream>>>(x, Ob, gamma, beta, (void*)H1);
  gemm_bt_kernel<1><<<gg, blk, 0, stream>>>(H1, WfT, bfb, (void*)H2);
  ln_kernel<0><<<dim3(4096), blk, 0, stream>>>(H2, Ob, gamma, beta, d_out);
}

// Round 2
// 494.973 us; speedup vs baseline: 1.2021x; 1.2021x over previous
//
#include <hip/hip_runtime.h>

// B=2, S=2048, D=2048, H=16, DH=128. fp32 in/out, bf16 MFMA internally.
// Pipeline: cast x -> W transposes -> Q/K GEMMs + V GEMM (writes V^T directly)
//           -> flash attention (S^T trick: softmax axis in-lane) -> LN1 -> FF GEMM -> LN2.
// O kept in [B,H,S,DH]; reference's "buggy concat" is a flat view of that as [B,S,D].

#define B_ 2
#define S_ 2048
#define D_ 2048
#define H_ 16
#define DH_ 128

typedef __attribute__((ext_vector_type(8))) short s16x8;
typedef __attribute__((ext_vector_type(4))) float f32x4;
typedef __attribute__((ext_vector_type(4))) unsigned short u16x4;

#define MFMA16(a, b, c) __builtin_amdgcn_mfma_f32_16x16x32_bf16(a, b, c, 0, 0, 0)

__device__ inline unsigned short f2bf(float f) {
  union { float f; unsigned u; } x; x.f = f;
  unsigned r = (x.u + 0x7fffu + ((x.u >> 16) & 1u)) >> 16;  // RNE
  return (unsigned short)r;
}
__device__ inline float bf2f(unsigned short u) {
  union { unsigned u; float f; } x; x.u = ((unsigned)u) << 16;
  return x.f;
}
// pack two f32 -> two bf16 in one dword (round-half-up via +0x8000, then v_perm)
__device__ inline unsigned pack2bf(float a, float b) {
  unsigned ua = __builtin_bit_cast(unsigned, a) + 0x8000u;
  unsigned ub = __builtin_bit_cast(unsigned, b) + 0x8000u;
  return __builtin_amdgcn_perm(ub, ua, 0x07060302u);  // {a.hi16, b.hi16}
}

__device__ inline void gld_lds16(const void* g, void* l) {
  __builtin_amdgcn_global_load_lds(
      (__attribute__((address_space(1))) void*)g,
      (__attribute__((address_space(3))) void*)l, 16, 0, 0);
}

// ---------------------------------------------------------------- cast x
__global__ __launch_bounds__(256) void cast_x_kernel(
    const float* __restrict__ x, unsigned short* __restrict__ xb) {
  int i = (blockIdx.x * 256 + threadIdx.x) * 4;
  float4 v = *(const float4*)&x[i];
  u16x4 o;
  o.x = f2bf(v.x); o.y = f2bf(v.y); o.z = f2bf(v.z); o.w = f2bf(v.w);
  *(u16x4*)&xb[i] = o;
}

// ------------------------------------------- weight transpose+cast: WT[n][k]=W[k][n]
__global__ __launch_bounds__(256) void transpose_w_kernel(
    const float* __restrict__ W, unsigned short* __restrict__ WT) {
  int t = threadIdx.x;
  int n0 = blockIdx.x * 64, k0 = blockIdx.y * 64;
  int cl = t & 15, rw = t >> 4;
#pragma unroll
  for (int p = 0; p < 4; ++p) {
    int k = k0 + rw + p * 16;
    float4 v = *(const float4*)&W[k * D_ + n0 + cl * 4];
    WT[(n0 + cl * 4 + 0) * D_ + k] = f2bf(v.x);
    WT[(n0 + cl * 4 + 1) * D_ + k] = f2bf(v.y);
    WT[(n0 + cl * 4 + 2) * D_ + k] = f2bf(v.z);
    WT[(n0 + cl * 4 + 3) * D_ + k] = f2bf(v.w);
  }
}

// ------------------------------------------- GEMM: C[4096][2048] = A * BT^T + bias
// MODE 0: bf16 row-major ((acc+bias)*oscale). MODE 1: fp32 row-major.
// MODE 2: bf16 written transposed per-head: VT[(b*16+h)*128+d][s].
template <int MODE>
__global__ __launch_bounds__(256) void gemm_bt_kernel(
    const unsigned short* __restrict__ A, const unsigned short* __restrict__ BT,
    const float* __restrict__ bias, void* __restrict__ Cout, float oscale) {
  __shared__ short As[128 * 32];
  __shared__ short Bs[128 * 32];
  int t = threadIdx.x, lane = t & 63, w = t >> 6;
  int nl = lane & 15, q = lane >> 4;
  int m0 = blockIdx.y * 128, n0 = blockIdx.x * 128;
  int wr = (w >> 1) * 64, wc = (w & 1) * 64;

  f32x4 acc[4][4];
  f32x4 z4 = {0.f, 0.f, 0.f, 0.f};
#pragma unroll
  for (int i = 0; i < 4; ++i)
#pragma unroll
    for (int j = 0; j < 4; ++j) acc[i][j] = z4;

  for (int kk = 0; kk < 2048; kk += 32) {
    __syncthreads();
#pragma unroll
    for (int i2 = 0; i2 < 2; ++i2) {
      int c = t + 256 * i2;
      int row = c >> 2, dc = c & 3;
      gld_lds16(&A[(m0 + row) * 2048 + kk + dc * 8], &As[c * 8]);
      gld_lds16(&BT[(n0 + row) * 2048 + kk + dc * 8], &Bs[c * 8]);
    }
    __syncthreads();
    s16x8 af[4], bf[4];
#pragma unroll
    for (int i = 0; i < 4; ++i)
      af[i] = *(const s16x8*)&As[(wr + i * 16 + nl) * 32 + q * 8];
#pragma unroll
    for (int j = 0; j < 4; ++j)
      bf[j] = *(const s16x8*)&Bs[(wc + j * 16 + nl) * 32 + q * 8];
#pragma unroll
    for (int i = 0; i < 4; ++i)
#pragma unroll
      for (int j = 0; j < 4; ++j) acc[i][j] = MFMA16(af[i], bf[j], acc[i][j]);
  }
#pragma unroll
  for (int i = 0; i < 4; ++i)
#pragma unroll
    for (int j = 0; j < 4; ++j) {
      int row = m0 + wr + i * 16 + q * 4;
      int col = n0 + wc + j * 16 + nl;
      float bv = bias[col];
      float v[4];
#pragma unroll
      for (int r = 0; r < 4; ++r) v[r] = (acc[i][j][r] + bv) * oscale;
      if (MODE == 1) {
#pragma unroll
        for (int r = 0; r < 4; ++r)
          ((float*)Cout)[(row + r) * 2048 + col] = v[r];
      } else if (MODE == 0) {
#pragma unroll
        for (int r = 0; r < 4; ++r)
          ((unsigned short*)Cout)[(row + r) * 2048 + col] = f2bf(v[r]);
      } else {
        unsigned d0 = pack2bf(v[0], v[1]), d1 = pack2bf(v[2], v[3]);
        long idx = ((long)(((row >> 11) * 16 + (col >> 7)) * 128 + (col & 127))) * 2048 +
                   (row & 2047);
        *(uint2*)&((unsigned short*)Cout)[idx] = (uint2){d0, d1};
      }
    }
}

// ------------------------------------------- flash attention (S^T trick)
// Block = (bh, 128 q rows). 4 waves x 32 qrows (t2=2 subtiles of 16).
// Per KV-tile of 64: accS = K*Q^T -> D[m=kv][n=qrow]: lane(q,nl) holds 16 kv
// values for qrow=nl -> in-lane softmax + 2 shuffles. P packed to LDS with
// XOR-swizzled [128][64] layout (b64 writes, b128 reads, conflict-free).
// O accumulated as O^T[d][qrow] via accO = MFMA(vf, pf).
__global__ __launch_bounds__(256, 2) void attn_kernel(
    const unsigned short* __restrict__ Q, const unsigned short* __restrict__ K,
    const unsigned short* __restrict__ VT, unsigned short* __restrict__ O) {
  __shared__ short Ks[4 * 64 * 32];  // 16KB [kc][kv 0..63][32]
  __shared__ short Vs[128 * 64];     // 16KB chunk-swizzled [d][kv]
  __shared__ short Ps[128 * 64];     // 16KB [qrow][kv], 16B-chunk XOR swizzle
  int t = threadIdx.x, lane = t & 63, w = t >> 6;
  int nl = lane & 15, q = lane >> 4;
  int bx = blockIdx.x;
  int qb = bx & 15, bh = bx >> 4;
  int b = bh >> 4, h = bh & 15;

  // Q fragments (pre-scaled by 1/sqrt(DH)*log2e in the Q GEMM epilogue)
  s16x8 qf[2][4];
  int qrow = b * S_ + qb * 128 + w * 32;
#pragma unroll
  for (int t2 = 0; t2 < 2; ++t2)
#pragma unroll
    for (int kc = 0; kc < 4; ++kc)
      qf[t2][kc] = *(const s16x8*)&Q[(qrow + t2 * 16 + nl) * D_ + h * DH_ + kc * 32 + q * 8];

  f32x4 z4 = {0.f, 0.f, 0.f, 0.f};
  f32x4 accO[2][8];
  float m_i[2] = {-1e30f, -1e30f}, l_i[2] = {0.f, 0.f};
#pragma unroll
  for (int t2 = 0; t2 < 2; ++t2)
#pragma unroll
    for (int n8 = 0; n8 < 8; ++n8) accO[t2][n8] = z4;

  int swz = nl & 7;

  for (int kv = 0; kv < S_; kv += 64) {
    __syncthreads();
#pragma unroll
    for (int i2 = 0; i2 < 4; ++i2) {
      int c = t + 256 * i2;
      {
        int kc = c >> 8, rem = c & 255, s = rem >> 2, dc = rem & 3;
        gld_lds16(&K[(b * S_ + kv + s) * D_ + h * DH_ + kc * 32 + dc * 8], &Ks[c * 8]);
      }
      {
        int d = c >> 3, cp = c & 7, cs = cp ^ (d & 7);
        gld_lds16(&VT[((long)(bh * DH_ + d)) * S_ + kv + cs * 8], &Vs[c * 8]);
      }
    }
    __syncthreads();

    // S^T = K Q^T : accS[t2][nkv], lane holds kv = nkv*16 + q*4 + r, qrow = nl
    f32x4 accS[2][4];
#pragma unroll
    for (int t2 = 0; t2 < 2; ++t2)
#pragma unroll
      for (int n = 0; n < 4; ++n) accS[t2][n] = z4;
#pragma unroll
    for (int kc = 0; kc < 4; ++kc) {
      s16x8 kf[4];
#pragma unroll
      for (int n = 0; n < 4; ++n)
        kf[n] = *(const s16x8*)&Ks[kc * 2048 + (n * 16 + nl) * 32 + q * 8];
#pragma unroll
      for (int t2 = 0; t2 < 2; ++t2)
#pragma unroll
        for (int n = 0; n < 4; ++n)
          accS[t2][n] = MFMA16(kf[n], qf[t2][kc], accS[t2][n]);
    }

    // online softmax, per-lane scalar state
#pragma unroll
    for (int t2 = 0; t2 < 2; ++t2) {
      float mx = -1e30f;
#pragma unroll
      for (int n = 0; n < 4; ++n)
#pragma unroll
        for (int r = 0; r < 4; ++r) mx = fmaxf(mx, accS[t2][n][r]);
      mx = fmaxf(mx, __shfl_xor(mx, 16));
      mx = fmaxf(mx, __shfl_xor(mx, 32));
      float mnew = fmaxf(m_i[t2], mx);
      float alpha = __builtin_amdgcn_exp2f(m_i[t2] - mnew);
      m_i[t2] = mnew;
      float ps = 0.f;
#pragma unroll
      for (int n = 0; n < 4; ++n)
#pragma unroll
        for (int r = 0; r < 4; ++r) {
          float p = __builtin_amdgcn_exp2f(accS[t2][n][r] - mnew);
          accS[t2][n][r] = p;
          ps += p;
        }
      ps += __shfl_xor(ps, 16);
      ps += __shfl_xor(ps, 32);
      l_i[t2] = l_i[t2] * alpha + ps;
      if (__any(alpha < 1.0f)) {
#pragma unroll
        for (int n8 = 0; n8 < 8; ++n8) accO[t2][n8] *= alpha;
      }
      // pack P -> Ps[qrow][kv] (4 bf16 along kv per b64 write)
      int prow = (w * 32 + t2 * 16 + nl) * 64;
#pragma unroll
      for (int n = 0; n < 4; ++n) {
        unsigned d0 = pack2bf(accS[t2][n][0], accS[t2][n][1]);
        unsigned d1 = pack2bf(accS[t2][n][2], accS[t2][n][3]);
        int c8 = q + 4 * n;
        int off = prow + (((c8 >> 1) ^ swz) * 8 + (c8 & 1) * 4);
        *(uint2*)&Ps[off] = (uint2){d0, d1};
      }
    }

    // O^T += V^T P^T : accO[t2][d-tile]
#pragma unroll
    for (int ks = 0; ks < 2; ++ks) {
      s16x8 pf[2];
#pragma unroll
      for (int t2 = 0; t2 < 2; ++t2)
        pf[t2] = *(const s16x8*)&Ps[(w * 32 + t2 * 16 + nl) * 64 + ((4 * ks + q) ^ swz) * 8];
#pragma unroll
      for (int n8 = 0; n8 < 8; ++n8) {
        int d = n8 * 16 + nl;
        int cs = ks * 4 + q;
        int ci = d * 8 + (cs ^ (d & 7));
        s16x8 vf = *(const s16x8*)&Vs[ci * 8];
#pragma unroll
        for (int t2 = 0; t2 < 2; ++t2)
          accO[t2][n8] = MFMA16(vf, pf[t2], accO[t2][n8]);
      }
    }
  }

  // normalize + store O[bh][s][d] (8B packed stores)
#pragma unroll
  for (int t2 = 0; t2 < 2; ++t2) {
    float inv = 1.0f / l_i[t2];
    int s = qb * 128 + w * 32 + t2 * 16 + nl;
    unsigned short* orow = &O[((long)(bh * S_ + s)) * DH_];
#pragma unroll
    for (int n8 = 0; n8 < 8; ++n8) {
      unsigned d0 = pack2bf(accO[t2][n8][0] * inv, accO[t2][n8][1] * inv);
      unsigned d1 = pack2bf(accO[t2][n8][2] * inv, accO[t2][n8][3] * inv);
      *(uint2*)&orow[n8 * 16 + q * 4] = (uint2){d0, d1};
    }
  }
}

// ------------------------------------------- LayerNorm: out = LN(A + O_flat)*gamma + beta
template <int OUTBF>
__global__ __launch_bounds__(256) void ln_kernel(
    const float* __restrict__ A, const unsigned short* __restrict__ Ob,
    const float* __restrict__ gamma, const float* __restrict__ beta,
    void* __restrict__ out) {
  int row = blockIdx.x, t = threadIdx.x;
  int lane = t & 63, w = t >> 6;
  float v[8], s = 0.f, s2 = 0.f;
#pragma unroll
  for (int p = 0; p < 8; ++p) {
    int c = t + p * 256;
    float a = A[row * D_ + c] + bf2f(Ob[row * D_ + c]);
    v[p] = a; s += a; s2 += a * a;
  }
#pragma unroll
  for (int mk = 32; mk >= 1; mk >>= 1) {
    s += __shfl_xor(s, mk);
    s2 += __shfl_xor(s2, mk);
  }
  __shared__ float red[8];
  if (lane == 0) { red[w * 2] = s; red[w * 2 + 1] = s2; }
  __syncthreads();
  s = red[0] + red[2] + red[4] + red[6];
  s2 = red[1] + red[3] + red[5] + red[7];
  float mu = s * (1.0f / D_);
  float var = s2 * (1.0f / D_) - mu * mu;
  float rs = rsqrtf(var + 1e-5f);
#pragma unroll
  for (int p = 0; p < 8; ++p) {
    int c = t + p * 256;
    float o = (v[p] - mu) * rs * gamma[c] + beta[c];
    if (OUTBF)
      ((unsigned short*)out)[row * D_ + c] = f2bf(o);
    else
      ((float*)out)[row * D_ + c] = o;
  }
}

// ------------------------------------------- launch
extern "C" void kernel_launch(void* const* d_in, const int* in_sizes, int n_in,
                              void* d_out, int out_size, void* d_ws, size_t ws_size,
                              hipStream_t stream) {
  const float* x     = (const float*)d_in[0];
  const float* wq    = (const float*)d_in[1];
  const float* bq    = (const float*)d_in[2];
  const float* wk    = (const float*)d_in[3];
  const float* bk    = (const float*)d_in[4];
  const float* wv    = (const float*)d_in[5];
  const float* bv    = (const float*)d_in[6];
  const float* wf    = (const float*)d_in[7];
  const float* bfb   = (const float*)d_in[8];
  const float* gamma = (const float*)d_in[9];
  const float* beta  = (const float*)d_in[10];

  unsigned short* ws  = (unsigned short*)d_ws;
  unsigned short* WqT = ws;
  unsigned short* WkT = ws + 4194304;
  unsigned short* WvT = ws + 8388608;
  unsigned short* WfT = ws + 12582912;
  unsigned short* Xb  = ws + 16777216;
  unsigned short* Qb  = ws + 25165824;
  unsigned short* Kb  = ws + 33554432;
  unsigned short* Vt  = ws + 41943040;          // V^T written directly by V GEMM
  unsigned short* Ob  = Xb;                     // O over Xb (dead after QKV GEMMs)
  unsigned short* H1  = Kb;                     // h1 over Kb (dead after attn)
  float* H2 = (float*)(ws + 41943040);          // h2 fp32 over Vt + 16MB (dead after attn)

  const float scl2 = 0.08838834764831845f * 1.4426950408889634f;  // 1/sqrt(DH)*log2e

  dim3 blk(256);
  cast_x_kernel<<<dim3(8192), blk, 0, stream>>>(x, Xb);
  dim3 tg(32, 32);
  transpose_w_kernel<<<tg, blk, 0, stream>>>(wq, WqT);
  transpose_w_kernel<<<tg, blk, 0, stream>>>(wk, WkT);
  transpose_w_kernel<<<tg, blk, 0, stream>>>(wv, WvT);
  transpose_w_kernel<<<tg, blk, 0, stream>>>(wf, WfT);

  dim3 gg(16, 32);
  gemm_bt_kernel<0><<<gg, blk, 0, stream>>>(Xb, WqT, bq, (void*)Qb, scl2);
  gemm_bt_kernel<0><<<gg, blk, 0, stream>>>(Xb, WkT, bk, (void*)Kb, 1.0f);
  gemm_bt_kernel<2><<<gg, blk, 0, stream>>>(Xb, WvT, bv, (void*)Vt, 1.0f);

  attn_kernel<<<dim3(512), blk, 0, stream>>>(Qb, Kb, Vt, Ob);

  ln_kernel<1><<<dim3(4096), blk, 0, stream>>>(x, Ob, gamma, beta, (void*)H1);
  gemm_bt_kernel<1><<<gg, blk, 0, stream>>>(H1, WfT, bfb, (void*)H2, 1.0f);
  ln_kernel<0><<<dim3(4096), blk, 0, stream>>>(H2, Ob, gamma, beta, d_out);
}

// Round 3
// 450.722 us; speedup vs baseline: 1.3201x; 1.0982x over previous
//
#include <hip/hip_runtime.h>

// B=2, S=2048, D=2048, H=16, DH=128. fp32 in/out, bf16 MFMA internally.
// cast x -> fused W transposes -> fused QKV GEMM (V written transposed) ->
// flash attention (S^T softmax-in-lane, double-buffered K/V staging) ->
// LN1 -> FF GEMM -> LN2.
// O kept in [B,H,S,DH]; reference's "buggy concat" is a flat view as [B,S,D].

#define B_ 2
#define S_ 2048
#define D_ 2048
#define H_ 16
#define DH_ 128

typedef __attribute__((ext_vector_type(8))) short s16x8;
typedef __attribute__((ext_vector_type(4))) float f32x4;
typedef __attribute__((ext_vector_type(4))) unsigned short u16x4;

#define MFMA16(a, b, c) __builtin_amdgcn_mfma_f32_16x16x32_bf16(a, b, c, 0, 0, 0)

__device__ inline unsigned short f2bf(float f) {
  union { float f; unsigned u; } x; x.f = f;
  unsigned r = (x.u + 0x7fffu + ((x.u >> 16) & 1u)) >> 16;  // RNE
  return (unsigned short)r;
}
__device__ inline float bf2f(unsigned short u) {
  union { unsigned u; float f; } x; x.u = ((unsigned)u) << 16;
  return x.f;
}
__device__ inline unsigned pack2bf(float a, float b) {
  unsigned ua = __builtin_bit_cast(unsigned, a) + 0x8000u;
  unsigned ub = __builtin_bit_cast(unsigned, b) + 0x8000u;
  return __builtin_amdgcn_perm(ub, ua, 0x07060302u);  // {a.hi16, b.hi16}
}

__device__ inline void gld_lds16(const void* g, void* l) {
  __builtin_amdgcn_global_load_lds(
      (__attribute__((address_space(1))) void*)g,
      (__attribute__((address_space(3))) void*)l, 16, 0, 0);
}

// ---------------------------------------------------------------- cast x
__global__ __launch_bounds__(256) void cast_x_kernel(
    const float* __restrict__ x, unsigned short* __restrict__ xb) {
  int i = (blockIdx.x * 256 + threadIdx.x) * 4;
  float4 v = *(const float4*)&x[i];
  u16x4 o;
  o.x = f2bf(v.x); o.y = f2bf(v.y); o.z = f2bf(v.z); o.w = f2bf(v.w);
  *(u16x4*)&xb[i] = o;
}

// ------------------------------------------- fused weight transpose+cast x4
__global__ __launch_bounds__(256) void transpose_w4_kernel(
    const float* __restrict__ w0, const float* __restrict__ w1,
    const float* __restrict__ w2, const float* __restrict__ w3,
    unsigned short* __restrict__ o0, unsigned short* __restrict__ o1,
    unsigned short* __restrict__ o2, unsigned short* __restrict__ o3) {
  int z = blockIdx.z;
  const float* W = z == 0 ? w0 : z == 1 ? w1 : z == 2 ? w2 : w3;
  unsigned short* WT = z == 0 ? o0 : z == 1 ? o1 : z == 2 ? o2 : o3;
  int t = threadIdx.x;
  int n0 = blockIdx.x * 64, k0 = blockIdx.y * 64;
  int cl = t & 15, rw = t >> 4;
#pragma unroll
  for (int p = 0; p < 4; ++p) {
    int k = k0 + rw + p * 16;
    float4 v = *(const float4*)&W[k * D_ + n0 + cl * 4];
    WT[(n0 + cl * 4 + 0) * D_ + k] = f2bf(v.x);
    WT[(n0 + cl * 4 + 1) * D_ + k] = f2bf(v.y);
    WT[(n0 + cl * 4 + 2) * D_ + k] = f2bf(v.z);
    WT[(n0 + cl * 4 + 3) * D_ + k] = f2bf(v.w);
  }
}

// ------------------------------------------- fused QKV GEMM
// grid (48, 32): blockIdx.x>>4 selects weight (0=Q,1=K,2=V). Q scaled by
// 1/sqrt(DH)*log2e; V written transposed per-head VT[(b*16+h)*128+d][s].
__global__ __launch_bounds__(256) void gemm_qkv_kernel(
    const unsigned short* __restrict__ A, const unsigned short* __restrict__ W0,
    const unsigned short* __restrict__ W1, const unsigned short* __restrict__ W2,
    const float* __restrict__ b0, const float* __restrict__ b1,
    const float* __restrict__ b2, unsigned short* __restrict__ Qb,
    unsigned short* __restrict__ Kb, unsigned short* __restrict__ Vt,
    float qscale) {
  __shared__ short As[128 * 32];
  __shared__ short Bs[128 * 32];
  int wi = blockIdx.x >> 4;
  int n0 = (blockIdx.x & 15) * 128;
  const unsigned short* BT = wi == 0 ? W0 : wi == 1 ? W1 : W2;
  const float* bias = wi == 0 ? b0 : wi == 1 ? b1 : b2;
  float oscale = wi == 0 ? qscale : 1.0f;

  int t = threadIdx.x, lane = t & 63, w = t >> 6;
  int nl = lane & 15, q = lane >> 4;
  int m0 = blockIdx.y * 128;
  int wr = (w >> 1) * 64, wc = (w & 1) * 64;

  f32x4 acc[4][4];
  f32x4 z4 = {0.f, 0.f, 0.f, 0.f};
#pragma unroll
  for (int i = 0; i < 4; ++i)
#pragma unroll
    for (int j = 0; j < 4; ++j) acc[i][j] = z4;

  for (int kk = 0; kk < 2048; kk += 32) {
    __syncthreads();
#pragma unroll
    for (int i2 = 0; i2 < 2; ++i2) {
      int c = t + 256 * i2;
      int row = c >> 2, dc = c & 3;
      gld_lds16(&A[(m0 + row) * 2048 + kk + dc * 8], &As[c * 8]);
      gld_lds16(&BT[(n0 + row) * 2048 + kk + dc * 8], &Bs[c * 8]);
    }
    __syncthreads();
    s16x8 af[4], bf[4];
#pragma unroll
    for (int i = 0; i < 4; ++i)
      af[i] = *(const s16x8*)&As[(wr + i * 16 + nl) * 32 + q * 8];
#pragma unroll
    for (int j = 0; j < 4; ++j)
      bf[j] = *(const s16x8*)&Bs[(wc + j * 16 + nl) * 32 + q * 8];
#pragma unroll
    for (int i = 0; i < 4; ++i)
#pragma unroll
      for (int j = 0; j < 4; ++j) acc[i][j] = MFMA16(af[i], bf[j], acc[i][j]);
  }
#pragma unroll
  for (int i = 0; i < 4; ++i)
#pragma unroll
    for (int j = 0; j < 4; ++j) {
      int row = m0 + wr + i * 16 + q * 4;
      int col = n0 + wc + j * 16 + nl;
      float bv = bias[col];
      float v[4];
#pragma unroll
      for (int r = 0; r < 4; ++r) v[r] = (acc[i][j][r] + bv) * oscale;
      if (wi == 2) {
        unsigned d0 = pack2bf(v[0], v[1]), d1 = pack2bf(v[2], v[3]);
        long idx = ((long)(((row >> 11) * 16 + (col >> 7)) * 128 + (col & 127))) * 2048 +
                   (row & 2047);
        *(uint2*)&Vt[idx] = (uint2){d0, d1};
      } else {
        unsigned short* out = wi == 0 ? Qb : Kb;
#pragma unroll
        for (int r = 0; r < 4; ++r)
          out[(row + r) * 2048 + col] = f2bf(v[r]);
      }
    }
}

// ------------------------------------------- FF GEMM (fp32 out)
__global__ __launch_bounds__(256) void gemm_ff_kernel(
    const unsigned short* __restrict__ A, const unsigned short* __restrict__ BT,
    const float* __restrict__ bias, float* __restrict__ Cout) {
  __shared__ short As[128 * 32];
  __shared__ short Bs[128 * 32];
  int t = threadIdx.x, lane = t & 63, w = t >> 6;
  int nl = lane & 15, q = lane >> 4;
  int m0 = blockIdx.y * 128, n0 = blockIdx.x * 128;
  int wr = (w >> 1) * 64, wc = (w & 1) * 64;

  f32x4 acc[4][4];
  f32x4 z4 = {0.f, 0.f, 0.f, 0.f};
#pragma unroll
  for (int i = 0; i < 4; ++i)
#pragma unroll
    for (int j = 0; j < 4; ++j) acc[i][j] = z4;

  for (int kk = 0; kk < 2048; kk += 32) {
    __syncthreads();
#pragma unroll
    for (int i2 = 0; i2 < 2; ++i2) {
      int c = t + 256 * i2;
      int row = c >> 2, dc = c & 3;
      gld_lds16(&A[(m0 + row) * 2048 + kk + dc * 8], &As[c * 8]);
      gld_lds16(&BT[(n0 + row) * 2048 + kk + dc * 8], &Bs[c * 8]);
    }
    __syncthreads();
    s16x8 af[4], bf[4];
#pragma unroll
    for (int i = 0; i < 4; ++i)
      af[i] = *(const s16x8*)&As[(wr + i * 16 + nl) * 32 + q * 8];
#pragma unroll
    for (int j = 0; j < 4; ++j)
      bf[j] = *(const s16x8*)&Bs[(wc + j * 16 + nl) * 32 + q * 8];
#pragma unroll
    for (int i = 0; i < 4; ++i)
#pragma unroll
      for (int j = 0; j < 4; ++j) acc[i][j] = MFMA16(af[i], bf[j], acc[i][j]);
  }
#pragma unroll
  for (int i = 0; i < 4; ++i)
#pragma unroll
    for (int j = 0; j < 4; ++j) {
      int row = m0 + wr + i * 16 + q * 4;
      int col = n0 + wc + j * 16 + nl;
      float bv = bias[col];
#pragma unroll
      for (int r = 0; r < 4; ++r)
        Cout[(row + r) * 2048 + col] = acc[i][j][r] + bv;
    }
}

// ------------------------------------------- flash attention (S^T, dbuf staging)
// Block = (bh, 128 q rows), 4 waves x 32 qrows. KV tiles of 64, K/V staged
// into double-buffered LDS (statically distinct arrays so the compiler can
// disambiguate: no vmcnt(0) before ds_reads of the other buffer). Each
// barrier drains loads issued one full compute-phase earlier -> cheap.
__global__ __launch_bounds__(256, 2) void attn_kernel(
    const unsigned short* __restrict__ Q, const unsigned short* __restrict__ K,
    const unsigned short* __restrict__ VT, unsigned short* __restrict__ O) {
  __shared__ short KsA[8192], KsB[8192];  // [kc][kv 0..63][32], 16KB each
  __shared__ short VsA[8192], VsB[8192];  // chunk-swizzled [d][kv], 16KB each
  __shared__ short Ps[8192];              // [qrow][kv], 16B-chunk XOR swizzle
  int t = threadIdx.x, lane = t & 63, w = t >> 6;
  int nl = lane & 15, q = lane >> 4;
  int bx = blockIdx.x;
  int qb = bx & 15, bh = bx >> 4;
  int b = bh >> 4, h = bh & 15;

  // Q fragments (pre-scaled by 1/sqrt(DH)*log2e in the QKV GEMM)
  s16x8 qf[2][4];
  int qrow = b * S_ + qb * 128 + w * 32;
#pragma unroll
  for (int t2 = 0; t2 < 2; ++t2)
#pragma unroll
    for (int kc = 0; kc < 4; ++kc)
      qf[t2][kc] = *(const s16x8*)&Q[(qrow + t2 * 16 + nl) * D_ + h * DH_ + kc * 32 + q * 8];

  f32x4 z4 = {0.f, 0.f, 0.f, 0.f};
  f32x4 accO[2][8];
  float m_i[2] = {-1e30f, -1e30f}, l_i[2] = {0.f, 0.f};
#pragma unroll
  for (int t2 = 0; t2 < 2; ++t2)
#pragma unroll
    for (int n8 = 0; n8 < 8; ++n8) accO[t2][n8] = z4;

  int swz = nl & 7;

  // hoisted staging pointers (advance by one KV tile per stage)
  const unsigned short* kp[4];
  const unsigned short* vp[4];
#pragma unroll
  for (int i2 = 0; i2 < 4; ++i2) {
    int c = t + 256 * i2;
    int kc = c >> 8, rem = c & 255, s = rem >> 2, dc = rem & 3;
    kp[i2] = K + (long)(b * S_ + s) * D_ + h * DH_ + kc * 32 + dc * 8;
    int d = c >> 3, cp = c & 7, cs = cp ^ (d & 7);
    vp[i2] = VT + (long)(bh * DH_ + d) * S_ + cs * 8;
  }

#define STAGE(bufK, bufV)                           \
  {                                                 \
    _Pragma("unroll") for (int i2 = 0; i2 < 4; ++i2) { \
      gld_lds16(kp[i2], &bufK[(t + 256 * i2) * 8]); \
      gld_lds16(vp[i2], &bufV[(t + 256 * i2) * 8]); \
      kp[i2] += 64 * D_;                            \
      vp[i2] += 64;                                 \
    }                                               \
  }

  auto compute = [&](const short* Ks, const short* Vs) {
    // S^T = K Q^T : lane holds kv = 16n + 4q + r for qrow = nl
    f32x4 accS[2][4];
#pragma unroll
    for (int t2 = 0; t2 < 2; ++t2)
#pragma unroll
      for (int n = 0; n < 4; ++n) accS[t2][n] = z4;
#pragma unroll
    for (int kc = 0; kc < 4; ++kc) {
      s16x8 kf[4];
#pragma unroll
      for (int n = 0; n < 4; ++n)
        kf[n] = *(const s16x8*)&Ks[kc * 2048 + (n * 16 + nl) * 32 + q * 8];
#pragma unroll
      for (int t2 = 0; t2 < 2; ++t2)
#pragma unroll
        for (int n = 0; n < 4; ++n)
          accS[t2][n] = MFMA16(kf[n], qf[t2][kc], accS[t2][n]);
    }

    // online softmax, per-lane scalar state
#pragma unroll
    for (int t2 = 0; t2 < 2; ++t2) {
      float mx = -1e30f;
#pragma unroll
      for (int n = 0; n < 4; ++n)
#pragma unroll
        for (int r = 0; r < 4; ++r) mx = fmaxf(mx, accS[t2][n][r]);
      mx = fmaxf(mx, __shfl_xor(mx, 16));
      mx = fmaxf(mx, __shfl_xor(mx, 32));
      float mnew = fmaxf(m_i[t2], mx);
      float alpha = __builtin_amdgcn_exp2f(m_i[t2] - mnew);
      m_i[t2] = mnew;
      float ps = 0.f;
#pragma unroll
      for (int n = 0; n < 4; ++n)
#pragma unroll
        for (int r = 0; r < 4; ++r) {
          float p = __builtin_amdgcn_exp2f(accS[t2][n][r] - mnew);
          accS[t2][n][r] = p;
          ps += p;
        }
      ps += __shfl_xor(ps, 16);
      ps += __shfl_xor(ps, 32);
      l_i[t2] = l_i[t2] * alpha + ps;
      if (__any(alpha < 1.0f)) {
#pragma unroll
        for (int n8 = 0; n8 < 8; ++n8) accO[t2][n8] *= alpha;
      }
      int prow = (w * 32 + t2 * 16 + nl) * 64;
#pragma unroll
      for (int n = 0; n < 4; ++n) {
        unsigned d0 = pack2bf(accS[t2][n][0], accS[t2][n][1]);
        unsigned d1 = pack2bf(accS[t2][n][2], accS[t2][n][3]);
        int c8 = q + 4 * n;
        int off = prow + (((c8 >> 1) ^ swz) * 8 + (c8 & 1) * 4);
        *(uint2*)&Ps[off] = (uint2){d0, d1};
      }
    }

    // O^T += V^T P^T
#pragma unroll
    for (int ks = 0; ks < 2; ++ks) {
      s16x8 pf[2];
#pragma unroll
      for (int t2 = 0; t2 < 2; ++t2)
        pf[t2] = *(const s16x8*)&Ps[(w * 32 + t2 * 16 + nl) * 64 + ((4 * ks + q) ^ swz) * 8];
#pragma unroll
      for (int n8 = 0; n8 < 8; ++n8) {
        int d = n8 * 16 + nl;
        int cs = ks * 4 + q;
        int ci = d * 8 + (cs ^ (d & 7));
        s16x8 vf = *(const s16x8*)&Vs[ci * 8];
#pragma unroll
        for (int t2 = 0; t2 < 2; ++t2)
          accO[t2][n8] = MFMA16(vf, pf[t2], accO[t2][n8]);
      }
    }
  };

  STAGE(KsA, VsA);  // tile 0
  for (int it = 0; it < 32; it += 2) {
    __syncthreads();
    STAGE(KsB, VsB);  // tile it+1 (lands during compute below)
    compute(KsA, VsA);
    __syncthreads();
    if (it + 2 < 32) STAGE(KsA, VsA);  // tile it+2
    compute(KsB, VsB);
  }
#undef STAGE

  // normalize + store O[bh][s][d] (8B packed stores)
#pragma unroll
  for (int t2 = 0; t2 < 2; ++t2) {
    float inv = 1.0f / l_i[t2];
    int s = qb * 128 + w * 32 + t2 * 16 + nl;
    unsigned short* orow = &O[((long)(bh * S_ + s)) * DH_];
#pragma unroll
    for (int n8 = 0; n8 < 8; ++n8) {
      unsigned d0 = pack2bf(accO[t2][n8][0] * inv, accO[t2][n8][1] * inv);
      unsigned d1 = pack2bf(accO[t2][n8][2] * inv, accO[t2][n8][3] * inv);
      *(uint2*)&orow[n8 * 16 + q * 4] = (uint2){d0, d1};
    }
  }
}

// ------------------------------------------- LayerNorm: out = LN(A + O_flat)*gamma + beta
template <int OUTBF>
__global__ __launch_bounds__(256) void ln_kernel(
    const float* __restrict__ A, const unsigned short* __restrict__ Ob,
    const float* __restrict__ gamma, const float* __restrict__ beta,
    void* __restrict__ out) {
  int row = blockIdx.x, t = threadIdx.x;
  int lane = t & 63, w = t >> 6;
  float v[8], s = 0.f, s2 = 0.f;
#pragma unroll
  for (int p = 0; p < 8; ++p) {
    int c = t + p * 256;
    float a = A[row * D_ + c] + bf2f(Ob[row * D_ + c]);
    v[p] = a; s += a; s2 += a * a;
  }
#pragma unroll
  for (int mk = 32; mk >= 1; mk >>= 1) {
    s += __shfl_xor(s, mk);
    s2 += __shfl_xor(s2, mk);
  }
  __shared__ float red[8];
  if (lane == 0) { red[w * 2] = s; red[w * 2 + 1] = s2; }
  __syncthreads();
  s = red[0] + red[2] + red[4] + red[6];
  s2 = red[1] + red[3] + red[5] + red[7];
  float mu = s * (1.0f / D_);
  float var = s2 * (1.0f / D_) - mu * mu;
  float rs = rsqrtf(var + 1e-5f);
#pragma unroll
  for (int p = 0; p < 8; ++p) {
    int c = t + p * 256;
    float o = (v[p] - mu) * rs * gamma[c] + beta[c];
    if (OUTBF)
      ((unsigned short*)out)[row * D_ + c] = f2bf(o);
    else
      ((float*)out)[row * D_ + c] = o;
  }
}

// ------------------------------------------- launch
extern "C" void kernel_launch(void* const* d_in, const int* in_sizes, int n_in,
                              void* d_out, int out_size, void* d_ws, size_t ws_size,
                              hipStream_t stream) {
  const float* x     = (const float*)d_in[0];
  const float* wq    = (const float*)d_in[1];
  const float* bq    = (const float*)d_in[2];
  const float* wk    = (const float*)d_in[3];
  const float* bk    = (const float*)d_in[4];
  const float* wv    = (const float*)d_in[5];
  const float* bv    = (const float*)d_in[6];
  const float* wf    = (const float*)d_in[7];
  const float* bfb   = (const float*)d_in[8];
  const float* gamma = (const float*)d_in[9];
  const float* beta  = (const float*)d_in[10];

  unsigned short* ws  = (unsigned short*)d_ws;
  unsigned short* WqT = ws;
  unsigned short* WkT = ws + 4194304;
  unsigned short* WvT = ws + 8388608;
  unsigned short* WfT = ws + 12582912;
  unsigned short* Xb  = ws + 16777216;
  unsigned short* Qb  = ws + 25165824;
  unsigned short* Kb  = ws + 33554432;
  unsigned short* Vt  = ws + 41943040;          // V^T written by fused QKV GEMM
  unsigned short* Ob  = Xb;                     // O over Xb (dead after QKV GEMMs)
  unsigned short* H1  = Kb;                     // h1 over Kb (dead after attn)
  float* H2 = (float*)(ws + 41943040);          // h2 fp32 over Vt+16MB (dead after attn)

  const float scl2 = 0.08838834764831845f * 1.4426950408889634f;  // 1/sqrt(DH)*log2e

  dim3 blk(256);
  cast_x_kernel<<<dim3(8192), blk, 0, stream>>>(x, Xb);
  transpose_w4_kernel<<<dim3(32, 32, 4), blk, 0, stream>>>(
      wq, wk, wv, wf, WqT, WkT, WvT, WfT);

  gemm_qkv_kernel<<<dim3(48, 32), blk, 0, stream>>>(
      Xb, WqT, WkT, WvT, bq, bk, bv, Qb, Kb, Vt, scl2);

  attn_kernel<<<dim3(512), blk, 0, stream>>>(Qb, Kb, Vt, Ob);

  ln_kernel<1><<<dim3(4096), blk, 0, stream>>>(x, Ob, gamma, beta, (void*)H1);
  gemm_ff_kernel<<<dim3(16, 32), blk, 0, stream>>>(H1, WfT, bfb, H2);
  ln_kernel<0><<<dim3(4096), blk, 0, stream>>>(H2, Ob, gamma, beta, d_out);
}